// Round 10
// baseline (241.544 us; speedup 1.0000x reference)
//
#include <hip/hip_runtime.h>

// Problem constants (fixed by setup_inputs): B=64, T=1024, V=128, S=256
constexpr int B_ = 64;
constexpr int T_ = 1024;
constexpr int V_ = 128;
constexpr int S_ = 256;
constexpr int SLOT = 130;            // floats/slot: 128 exp'd row + zero-pad @128 (+1 align)
constexpr int NSLOT = 16;            // slots/wave; max live write-read distance is 11
constexpr float INV_LN2 = 1.4426950408889634f;
constexpr float LN2 = 0.6931471805599453f;

// Workspace layout (floats): [0..63] per-b loss; [64 ..) dumps: fwd b*640,
// then bwd at +64*640; K exponents as ints after that (fwd [b], bwd [64+b]).
#define WS_DUMPF(W, b) ((W) + 64 + (size_t)(b) * 640)
#define WS_DUMPB(W, b) ((W) + 64 + 64 * 640 + (size_t)(b) * 640)
#define WS_KARR(W)     ((int*)((W) + 64 + 2 * 64 * 640))

// ---- DPP cross-lane helpers (pure VALU: no DS op, no lgkmcnt) ----
template <int CTRL>
__device__ __forceinline__ float dpp_mov0(float x) {
    // invalid source lanes receive old = 0 (wave_shr1: lane0 -> 0;
    // wave_shl1: lane63 -> 0) -- exactly the boundary fill the scan needs.
    return __int_as_float(__builtin_amdgcn_update_dpp(
        0, __float_as_int(x), CTRL, 0xF, 0xF, false));
}
template <int CTRL>
__device__ __forceinline__ float dpp_max(float x) {
    const float s = __int_as_float(__builtin_amdgcn_update_dpp(
        __float_as_int(x), __float_as_int(x), CTRL, 0xF, 0xF, false));
    return fmaxf(x, s);
}

// Wave-uniform rescale: pin wave max to 2^124 (R8-proven; cadence <= 8 rows).
// Wave-max via DPP reduce (row_shr 1/2/4/8 + bcast15/31 -> lane63).
__device__ __forceinline__ int wave_rescale(float a[10], int& K) {
    float mx = a[0];
    #pragma unroll
    for (int k = 1; k < 10; ++k) mx = fmaxf(mx, a[k]);
    mx = dpp_max<0x111>(mx);   // row_shr:1
    mx = dpp_max<0x112>(mx);   // row_shr:2
    mx = dpp_max<0x114>(mx);   // row_shr:4
    mx = dpp_max<0x118>(mx);   // row_shr:8
    mx = dpp_max<0x142>(mx);   // row_bcast:15
    mx = dpp_max<0x143>(mx);   // row_bcast:31 -> lane63 has wave-max
    const float mall = __int_as_float(
        __builtin_amdgcn_readlane(__float_as_int(mx), 63));
    int e;
    (void)frexpf(mall, &e);
    const int ks = (mall > 0.0f) ? (124 - e) : 0;
    #pragma unroll
    for (int k = 0; k < 10; ++k) a[k] = ldexpf(a[k], ks);
    K += ks;
    return ks;
}

// Pipelined per-wave phase helpers (macros keep ALL array indices literal
// after unroll -- rule #20: no runtime-indexed register arrays).
#define STAGE(ph, RBUF, RO) do {                                              \
    _Pragma("unroll")                                                         \
    for (int i_ = 0; i_ < 4; ++i_) {                                          \
        const int u_ = 4 * (ph) + 1 + i_;                                     \
        if (u_ <= U) {                                                        \
            const float e0_ = __builtin_exp2f(RBUF[(RO) + i_].x * INV_LN2);   \
            const float e1_ = __builtin_exp2f(RBUF[(RO) + i_].y * INV_LN2);   \
            *(float2*)&ring[(u_ & (NSLOT - 1)) * SLOT + 2 * lane] =           \
                make_float2(e0_, e1_);                                        \
        }                                                                     \
    } } while (0)

#define GISSUE(ph, GN) do {                                                   \
    _Pragma("unroll")                                                         \
    for (int i_ = 0; i_ < 4; ++i_) {                                          \
        const int u_ = 4 * (ph) + 1 + i_;                                     \
        if (u_ <= U) {                                                        \
            const float* rb_ = &ring[(u_ & (NSLOT - 1)) * SLOT];              \
            GN[i_ * 6 + 0] = rb_[0];          /* blank: uniform -> bcast */   \
            _Pragma("unroll")                                                 \
            for (int c_ = 0; c_ < 5; ++c_)                                    \
                GN[i_ * 6 + 1 + c_] = rb_[off[c_]];  /* masked -> pad 0 */    \
        }                                                                     \
    } } while (0)

#define CONSUME(ph, GC) do {                                                  \
    _Pragma("unroll")                                                         \
    for (int i_ = 0; i_ < 4; ++i_) {                                          \
        const int u_ = 4 * (ph) + 1 + i_;                                     \
        if (u_ <= U)                                                          \
            rowCore(make_float2(GC[i_ * 6 + 0], GC[i_ * 6 + 1]),              \
                    make_float2(GC[i_ * 6 + 2], GC[i_ * 6 + 3]),              \
                    make_float2(GC[i_ * 6 + 4], GC[i_ * 6 + 5]));             \
    } } while (0)

// R19: SELF-SUFFICIENT SCAN WAVES, CO-RESIDENT 2/SIMD.
// R13/R17/R18 all hit ~293cy/row with a LONE consumer wave per SIMD; R14's
// mono-wave hit 600 vs ~180 issue -- a consistent ~3x latency-exposure gap
// for solo waves. This kernel: (a) folds staging into the scan wave (2 exp +
// 1 ds_write/row, divergent ds_read gather -- both proven cheap in R18),
// zero synchronization (same-wave DS is in-order); (b) packs 8 independent
// scan waves per 512-thread WG so each SIMD hosts 2 waves that hide each
// other's dependency latency. 16 WGs total; wave (block*8+wid) owns scan
// (b = idx&63, dir = idx>>6). Private 16-slot LDS ring per wave; masked
// labels read a never-overwritten 0.0 pad at word 128 (replaces vmask mul).
__global__ __launch_bounds__(512) void ctc_scan(
    const float* __restrict__ lp,      // [B,T,V] natural-log softmax
    const int* __restrict__ in_len,    // [B]
    const int* __restrict__ tgt,       // [B,S]
    const int* __restrict__ tgt_len,   // [B]
    float* __restrict__ W)             // workspace
{
    const int wid  = threadIdx.x >> 6;
    const int lane = threadIdx.x & 63;
    const int idx  = blockIdx.x * 8 + wid;    // 0..127
    const int b    = idx & 63;
    const int dir  = idx >> 6;                // 0 = fwd, 1 = bwd

    __shared__ float ringAll[8 * NSLOT * SLOT];   // 66560 B
    float* ring = ringAll + wid * (NSLOT * SLOT);

    const int L  = tgt_len[b];        // 64..256
    const int Tb = in_len[b];         // 768..1024
    const float* lpb = lp + (size_t)b * T_ * V_;
    const int* tg = tgt + b * S_;

    const int tm = (Tb - 2) >> 1;
    const int Uf = tm;                // fwd steps: u=1..Uf (row t=u) -> alpha_tm
    const int Ub = Tb - 2 - tm;       // bwd steps: u=1..Ub (row t=Tb-1-u) -> g_{tm+1}
    const int U  = dir ? Ub : Uf;

    // zero-pad word 128 of each slot (row writes cover 0..127 only, so this
    // stays 0 forever; same-wave in-order DS makes it visible to all gathers)
    if (lane < NSLOT) ring[lane * SLOT + 128] = 0.0f;

    // per-lane constant gather offsets; masked -> pad (reads exact 0.0)
    int off[5];
    #pragma unroll
    for (int c = 0; c < 5; ++c) {
        const int j = 5 * lane + c;
        off[c] = (j < L) ? tg[j] : 128;
    }

    float2 RA[8], RB[8];              // global ping-pong chunk buffers
    auto issueChunk = [&](float2 (&R)[8], int cch) {
        #pragma unroll
        for (int i = 0; i < 8; ++i) {
            const int u = 8 * cch + 1 + i;
            if (u <= U) {
                const int t = dir ? (Tb - 1 - u) : u;
                R[i] = *(const float2*)(lpb + (size_t)t * V_ + 2 * lane);
            }
        }
    };

    float G0[24], G1[24];             // gathered rows, 2-phase ping-pong

    if (dir == 0) {
        // ======================= forward alpha =======================
        float skipf[5];
        #pragma unroll
        for (int c = 0; c < 5; ++c) {
            const int j = 5 * lane + c;
            skipf[c] = (j >= 1 && j < L && tg[j] != tg[j - 1]) ? 1.0f : 0.0f;
        }
        float a[10];
        #pragma unroll
        for (int k = 0; k < 10; ++k) a[k] = 0.0f;
        {
            const float p00 = __builtin_exp2f(lpb[0] * INV_LN2);
            const float p01 = __builtin_exp2f(lpb[tg[0]] * INV_LN2);
            if (lane == 0) { a[0] = p00; a[1] = p01; }
        }
        float u9n = 0.0f;             // inflow alpha_prev[s-1] for s=10*lane
        int K = 0;

        auto rowCore = [&](float2 c0, float2 c1, float2 c2) {
            const float u9 = u9n;
            const float p0 = c0.x;
            a[9] = (a[9] + a[8] + skipf[4] * a[7]) * c2.y;
            u9n = dpp_mov0<0x138>(a[9]);   // wave_shr:1 (lane0 -> 0)
            a[8] = (a[8] + a[7]) * p0;
            a[7] = (a[7] + a[6] + skipf[3] * a[5]) * c2.x;
            a[6] = (a[6] + a[5]) * p0;
            a[5] = (a[5] + a[4] + skipf[2] * a[3]) * c1.y;
            a[4] = (a[4] + a[3]) * p0;
            a[3] = (a[3] + a[2] + skipf[1] * a[1]) * c1.x;
            a[2] = (a[2] + a[1]) * p0;
            a[1] = (a[1] + a[0] + skipf[0] * u9) * c0.y;
            a[0] = (a[0] + u9) * p0;
        };

        // prologue: chunks 0,1 in flight; phase 0 staged+gathered; phase 1 staged
        issueChunk(RA, 0);
        issueChunk(RB, 1);
        STAGE(0, RA, 0);
        GISSUE(0, G0);
        STAGE(1, RA, 4);

        // 4-phase iterations: stage(h+2) | gissue(h+1) | consume(h); chunk
        // issues 2 phases ahead of first stage; rescale every 2 phases (8 rows)
        for (int hb = 0; 4 * hb + 1 <= U; hb += 4) {
            const int cb = hb >> 1;
            if (8 * (cb + 2) + 1 <= U) issueChunk(RA, cb + 2);
            STAGE(hb + 2, RB, 0); GISSUE(hb + 1, G1); CONSUME(hb + 0, G0);
            STAGE(hb + 3, RB, 4); GISSUE(hb + 2, G0); CONSUME(hb + 1, G1);
            { const int ks = wave_rescale(a, K); u9n = ldexpf(u9n, ks); }
            if (8 * (cb + 3) + 1 <= U) issueChunk(RB, cb + 3);
            STAGE(hb + 4, RA, 0); GISSUE(hb + 3, G1); CONSUME(hb + 2, G0);
            STAGE(hb + 5, RA, 4); GISSUE(hb + 4, G0); CONSUME(hb + 3, G1);
            { const int ks = wave_rescale(a, K); u9n = ldexpf(u9n, ks); }
        }

        float* dump = WS_DUMPF(W, b);
        #pragma unroll
        for (int k = 0; k < 10; ++k) dump[10 * lane + k] = a[k];
        if (lane == 0) WS_KARR(W)[b] = K;
    } else {
        // ======================= backward beta =======================
        float sB[5];                  // skip into s+2 (odd): label j = 5*lane+c+1
        #pragma unroll
        for (int c = 0; c < 5; ++c) {
            const int j = 5 * lane + c + 1;
            sB[c] = (j < L && tg[j] != tg[j - 1]) ? 1.0f : 0.0f;
        }
        float g[10];
        #pragma unroll
        for (int k = 0; k < 10; ++k) g[k] = 0.0f;
        {   // g_{Tb-1}: nonzero at s=2L (blank) and s=2L-1 (last label)
            const float pb = __builtin_exp2f(lpb[(size_t)(Tb - 1) * V_] * INV_LN2);
            const float pl = __builtin_exp2f(lpb[(size_t)(Tb - 1) * V_ + tg[L - 1]] * INV_LN2);
            #pragma unroll
            for (int k = 0; k < 10; ++k) {
                const int s = 10 * lane + k;
                if (s == 2 * L)     g[k] = pb;
                if (s == 2 * L - 1) g[k] = pl;
            }
        }
        float d0n = dpp_mov0<0x130>(g[0]);   // wave_shl:1 (lane63 -> 0)
        float d1n = dpp_mov0<0x130>(g[1]);
        int K = 0;

        auto rowCore = [&](float2 c0, float2 c1, float2 c2) {
            const float d0 = d0n, d1 = d1n;
            const float p0 = c0.x;
            g[0] = (g[0] + g[1]) * p0;
            g[1] = (g[1] + g[2] + sB[0] * g[3]) * c0.y;
            d0n = dpp_mov0<0x130>(g[0]);     // early-produce, pure VALU
            d1n = dpp_mov0<0x130>(g[1]);
            g[2] = (g[2] + g[3]) * p0;
            g[3] = (g[3] + g[4] + sB[1] * g[5]) * c1.x;
            g[4] = (g[4] + g[5]) * p0;
            g[5] = (g[5] + g[6] + sB[2] * g[7]) * c1.y;
            g[6] = (g[6] + g[7]) * p0;
            g[7] = (g[7] + g[8] + sB[3] * g[9]) * c2.x;
            g[8] = (g[8] + g[9]) * p0;
            g[9] = (g[9] + d0 + sB[4] * d1) * c2.y;
        };

        issueChunk(RA, 0);
        issueChunk(RB, 1);
        STAGE(0, RA, 0);
        GISSUE(0, G0);
        STAGE(1, RA, 4);

        for (int hb = 0; 4 * hb + 1 <= U; hb += 4) {
            const int cb = hb >> 1;
            if (8 * (cb + 2) + 1 <= U) issueChunk(RA, cb + 2);
            STAGE(hb + 2, RB, 0); GISSUE(hb + 1, G1); CONSUME(hb + 0, G0);
            STAGE(hb + 3, RB, 4); GISSUE(hb + 2, G0); CONSUME(hb + 1, G1);
            { const int ks = wave_rescale(g, K);
              d0n = ldexpf(d0n, ks); d1n = ldexpf(d1n, ks); }
            if (8 * (cb + 3) + 1 <= U) issueChunk(RB, cb + 3);
            STAGE(hb + 4, RA, 0); GISSUE(hb + 3, G1); CONSUME(hb + 2, G0);
            STAGE(hb + 5, RA, 4); GISSUE(hb + 4, G0); CONSUME(hb + 3, G1);
            { const int ks = wave_rescale(g, K);
              d0n = ldexpf(d0n, ks); d1n = ldexpf(d1n, ks); }
        }

        {   // combine: gext[s] = g[s] + g[s+1] + skip[s+2]*g[s+2] (ascending)
            const float d0 = d0n, d1 = d1n;
            g[0] = g[0] + g[1];
            g[1] = g[1] + g[2] + sB[0] * g[3];
            g[2] = g[2] + g[3];
            g[3] = g[3] + g[4] + sB[1] * g[5];
            g[4] = g[4] + g[5];
            g[5] = g[5] + g[6] + sB[2] * g[7];
            g[6] = g[6] + g[7];
            g[7] = g[7] + g[8] + sB[3] * g[9];
            g[8] = g[8] + g[9];
            g[9] = g[9] + d0 + sB[4] * d1;
        }
        float* dump = WS_DUMPB(W, b);
        #pragma unroll
        for (int k = 0; k < 10; ++k) dump[10 * lane + k] = g[k];
        if (lane == 0) WS_KARR(W)[64 + b] = K;
    }
}

// Join: one block per batch element, 64 lanes. Double-precision dot of the
// two dumps (factors span ~240 bits in f32 frames -- R7 lesson).
__global__ void ctc_join_kernel(const float* __restrict__ W_const,
                                const int* __restrict__ tgt_len,
                                float* __restrict__ lossArr) {
    const int b = blockIdx.x;
    const int lane = threadIdx.x;
    float* W = const_cast<float*>(W_const);
    const float* dA = WS_DUMPF(W, b);
    const float* dB = WS_DUMPB(W, b);
    double sum = 0.0;
    #pragma unroll
    for (int k = 0; k < 10; ++k)
        sum += (double)dA[10 * lane + k] * (double)dB[10 * lane + k];
    #pragma unroll
    for (int d = 1; d < 64; d <<= 1) sum += __shfl_xor(sum, d, 64);
    if (lane == 0) {
        const int L = tgt_len[b];
        const int KF = WS_KARR(W)[b];
        const int KB = WS_KARR(W)[64 + b];
        float loss = 0.0f;                     // infeasible (sum<=0) -> 0
        if (sum > 0.0) {
            const long long ub = __double_as_longlong(sum);
            const int ex = (int)((ub >> 52) & 2047) - 1023;
            const double f = __longlong_as_double(
                (ub & 0x000FFFFFFFFFFFFFLL) | 0x3FF0000000000000LL);
            const float ll2 = __builtin_log2f((float)f)
                            + (float)(ex - KF - KB);
            loss = -(ll2 * LN2);
            if (!(loss <= 1e29f)) loss = 0.0f; // zero_infinity
        }
        lossArr[b] = loss / (float)L;
    }
}

__global__ void ctc_reduce_kernel(const float* __restrict__ ws, float* __restrict__ out) {
    float v = ws[threadIdx.x];
    #pragma unroll
    for (int o = 32; o > 0; o >>= 1) v += __shfl_down(v, o);
    if (threadIdx.x == 0) out[0] = v / (float)B_;
}

extern "C" void kernel_launch(void* const* d_in, const int* in_sizes, int n_in,
                              void* d_out, int out_size, void* d_ws, size_t ws_size,
                              hipStream_t stream) {
    const float* lp      = (const float*)d_in[0];
    const int*   in_len  = (const int*)d_in[1];
    const int*   tgt     = (const int*)d_in[2];
    const int*   tgt_len = (const int*)d_in[3];
    float* W   = (float*)d_ws;                  // needs ~330 KB
    float* out = (float*)d_out;

    ctc_scan<<<16, 512, 0, stream>>>(lp, in_len, tgt, tgt_len, W);
    ctc_join_kernel<<<B_, 64, 0, stream>>>(W, tgt_len, W);   // writes W[0..63]
    ctc_reduce_kernel<<<1, 64, 0, stream>>>(W, out);
}

// Round 11
// 200.151 us; speedup vs baseline: 1.2068x; 1.2068x over previous
//
#include <hip/hip_runtime.h>

// Problem constants (fixed by setup_inputs): B=64, T=1024, V=128, S=256
constexpr int B_ = 64;
constexpr int T_ = 1024;
constexpr int V_ = 128;
constexpr int S_ = 256;
constexpr int GRING = 32;            // staged rows per ring (8 blocks of 4)
constexpr int NTAG = 8;
constexpr int ROWF = 384;            // floats per staged row: 3 planes x 64 lanes x float2
constexpr int NGW = 3;               // producer waves
constexpr float INV_LN2 = 1.4426950408889634f;
constexpr float LN2 = 0.6931471805599453f;

#define WG_SCOPE __HIP_MEMORY_SCOPE_WORKGROUP

__device__ __forceinline__ void poll_eq(int* p, int want) {
    // RELAXED: LDS is per-CU; producer drained ds_writes (lgkmcnt(0)) before tag.
    while (__hip_atomic_load(p, __ATOMIC_RELAXED, WG_SCOPE) != want)
        __builtin_amdgcn_s_sleep(1);
}

// ---- DPP cross-lane helpers (pure VALU: no DS op, no lgkmcnt) ----
template <int CTRL>
__device__ __forceinline__ float dpp_mov0(float x) {
    // invalid source lanes receive old = 0 (wave_shr1: lane0 -> 0;
    // wave_shl1: lane63 -> 0) -- exactly the boundary fill the scan needs.
    return __int_as_float(__builtin_amdgcn_update_dpp(
        0, __float_as_int(x), CTRL, 0xF, 0xF, false));
}
template <int CTRL>
__device__ __forceinline__ float dpp_max(float x) {
    const float s = __int_as_float(__builtin_amdgcn_update_dpp(
        __float_as_int(x), __float_as_int(x), CTRL, 0xF, 0xF, false));
    return fmaxf(x, s);
}

// Wave-uniform rescale: pin wave max to 2^124 (R8-proven; cadence <= 8 rows).
// Wave-max via DPP reduce (row_shr 1/2/4/8 + bcast15/31 -> lane63).
__device__ __forceinline__ int wave_rescale(float a[10], int& K) {
    float mx = a[0];
    #pragma unroll
    for (int k = 1; k < 10; ++k) mx = fmaxf(mx, a[k]);
    mx = dpp_max<0x111>(mx);   // row_shr:1
    mx = dpp_max<0x112>(mx);   // row_shr:2
    mx = dpp_max<0x114>(mx);   // row_shr:4
    mx = dpp_max<0x118>(mx);   // row_shr:8
    mx = dpp_max<0x142>(mx);   // row_bcast:15
    mx = dpp_max<0x143>(mx);   // row_bcast:31 -> lane63 has wave-max
    const float mall = __int_as_float(
        __builtin_amdgcn_readlane(__float_as_int(mx), 63));
    int e;
    (void)frexpf(mall, &e);
    const int ks = (mall > 0.0f) ? (124 - e) : 0;
    #pragma unroll
    for (int k = 0; k < 10; ++k) a[k] = ldexpf(a[k], ks);
    K += ks;
    return ks;
}

// R20: DUAL-SCAN CONSUMER (in-wave ILP). R13-R18 fixed the lone consumer
// at ~293cy/row (~65% stall: exposed dependent-op latency nothing fills).
// R19 showed hardware co-residency of 8 waves/CU saturates the DS pipe.
// This kernel fills the stalls INSIDE one wave: consumer runs fwd(b) and
// bwd(b) interleaved (independent chains, same length +-1, shared labels).
// 64 WGs x 4 waves: wave0 dual-consumer, waves 1-3 producers staging BOTH
// rings (R13 bpermute-gather economics). One tag per block covers both
// rings; single cons counter (both scans advance in lockstep). The join
// (fwd.beta dot) happens in-register at the end -- no join kernel, no
// global dumps. Protocol/math per direction byte-identical to R13/R17.
__global__ __launch_bounds__(256) void ctc_scan(
    const float* __restrict__ lp,      // [B,T,V] natural-log softmax
    const int* __restrict__ in_len,    // [B]
    const int* __restrict__ tgt,       // [B,S]
    const int* __restrict__ tgt_len,   // [B]
    float* __restrict__ loss)          // [B] per-batch loss / L
{
    const int b    = blockIdx.x;
    const int tid  = threadIdx.x;
    const int wid  = tid >> 6;
    const int lane = tid & 63;

    __shared__ float ringF[GRING * ROWF];     // 48 KB
    __shared__ float ringB[GRING * ROWF];     // 48 KB
    __shared__ int   tags[NTAG];
    __shared__ int   cons;

    const int L  = tgt_len[b];        // 64..256
    const int Tb = in_len[b];         // 768..1024
    const float* lpb = lp + (size_t)b * T_ * V_;
    const int* tg = tgt + b * S_;

    const int tm = (Tb - 2) >> 1;
    const int Uf = tm;                // fwd steps: u=1..Uf (row t=u) -> alpha_tm
    const int Ub = Tb - 2 - tm;       // bwd steps: u=1..Ub (row t=Tb-1-u); Ub in {Uf, Uf+1}
    const int Umax = Ub;              // Ub >= Uf always

    if (tid == 0) cons = 0;
    if (tid < NTAG) tags[tid] = -1;
    __syncthreads();

    if (wid >= 1) {
        // ======================= producers =======================
        // wave q handles blocks m == q (mod 3); block m = 4 fwd rows + 4 bwd
        // rows (both rings). Full-row coalesced load -> 2 exps -> in-register
        // bpermute gather -> 3x float2 contiguous per lane (R13 layout).
        const int q = wid - 1;                    // 0..2

        int   perm[5], oddc[5];
        float vmask[5];
        #pragma unroll
        for (int c = 0; c < 5; ++c) {
            const int j = 5 * lane + c;
            if (j < L) { const int lb = tg[j]; perm[c] = lb >> 1; oddc[c] = lb & 1; vmask[c] = 1.0f; }
            else       { perm[c] = 0; oddc[c] = 0; vmask[c] = 0.0f; }
        }

        float2 R0[8], R1[8];          // [0..3] fwd rows, [4..7] bwd rows
        auto issue = [&](float2 (&Rb)[8], int m) {
            #pragma unroll
            for (int r = 0; r < 4; ++r) {
                const int u = 4 * m + 1 + r;
                if (u <= Uf)
                    Rb[r] = *(const float2*)(lpb + (size_t)u * V_ + 2 * lane);
                if (u <= Ub)
                    Rb[4 + r] = *(const float2*)(lpb + (size_t)(Tb - 1 - u) * V_ + 2 * lane);
            }
        };
        auto emitRow = [&](float* ring, int slot, float2 Rv) {
            const float e0 = __builtin_exp2f(Rv.x * INV_LN2);
            const float e1 = __builtin_exp2f(Rv.y * INV_LN2);
            const float p0 = __int_as_float(
                __builtin_amdgcn_readfirstlane(__float_as_int(e0)));
            float gv[5];
            #pragma unroll
            for (int c = 0; c < 5; ++c) {
                const float lo = __shfl(e0, perm[c], 64);
                const float hi = __shfl(e1, perm[c], 64);
                gv[c] = vmask[c] * (oddc[c] ? hi : lo);
            }
            float* rb = ring + slot * ROWF;
            ((float2*)rb)[lane]         = make_float2(p0,    gv[0]);
            ((float2*)(rb + 128))[lane] = make_float2(gv[1], gv[2]);
            ((float2*)(rb + 256))[lane] = make_float2(gv[3], gv[4]);
        };
        auto process = [&](float2 (&Rb)[8], int m) {
            // ring-slot reuse gate: slot shared with block m-8
            while (__hip_atomic_load(&cons, __ATOMIC_RELAXED, WG_SCOPE) < 4 * m - 28)
                __builtin_amdgcn_s_sleep(1);
            #pragma unroll
            for (int r = 0; r < 4; ++r) {
                const int u = 4 * m + 1 + r;
                const int slot = (4 * m + r) & (GRING - 1);
                if (u <= Uf) emitRow(ringF, slot, Rb[r]);
                if (u <= Ub) emitRow(ringB, slot, Rb[4 + r]);
            }
            // drain LDS writes only (NOT vmcnt), then publish the tag.
            asm volatile("s_waitcnt lgkmcnt(0)" ::: "memory");
            if (lane == 0)
                __hip_atomic_store(&tags[m & (NTAG - 1)], m, __ATOMIC_RELAXED, WG_SCOPE);
        };

        int m = q;
        if (4 * m + 1 <= Umax) {
            issue(R0, m);
            if (4 * (m + NGW) + 1 <= Umax) issue(R1, m + NGW);
            while (true) {
                process(R0, m);
                if (4 * (m + 2 * NGW) + 1 <= Umax) issue(R0, m + 2 * NGW);
                m += NGW;
                if (4 * m + 1 > Umax) break;
                process(R1, m);
                if (4 * (m + 2 * NGW) + 1 <= Umax) issue(R1, m + 2 * NGW);
                m += NGW;
                if (4 * m + 1 > Umax) break;
            }
        }
        return;
    }

    // ======================= dual consumer (wave0) =======================
    // ---- forward state ----
    float skipf[5];
    #pragma unroll
    for (int c = 0; c < 5; ++c) {
        const int j = 5 * lane + c;
        skipf[c] = (j >= 1 && j < L && tg[j] != tg[j - 1]) ? 1.0f : 0.0f;
    }
    float a[10];
    #pragma unroll
    for (int k = 0; k < 10; ++k) a[k] = 0.0f;
    {
        const float p00 = __builtin_exp2f(lpb[0] * INV_LN2);
        const float p01 = __builtin_exp2f(lpb[tg[0]] * INV_LN2);
        if (lane == 0) { a[0] = p00; a[1] = p01; }
    }
    float u9n = 0.0f;
    int KF = 0;

    // ---- backward state ----
    float sB[5];
    #pragma unroll
    for (int c = 0; c < 5; ++c) {
        const int j = 5 * lane + c + 1;
        sB[c] = (j < L && tg[j] != tg[j - 1]) ? 1.0f : 0.0f;
    }
    float g[10];
    #pragma unroll
    for (int k = 0; k < 10; ++k) g[k] = 0.0f;
    {   // g_{Tb-1}: nonzero at s=2L (blank) and s=2L-1 (last label)
        const float pb = __builtin_exp2f(lpb[(size_t)(Tb - 1) * V_] * INV_LN2);
        const float pl = __builtin_exp2f(lpb[(size_t)(Tb - 1) * V_ + tg[L - 1]] * INV_LN2);
        #pragma unroll
        for (int k = 0; k < 10; ++k) {
            const int s = 10 * lane + k;
            if (s == 2 * L)     g[k] = pb;
            if (s == 2 * L - 1) g[k] = pl;
        }
    }
    float d0n = dpp_mov0<0x130>(g[0]);   // wave_shl:1 (lane63 -> 0)
    float d1n = dpp_mov0<0x130>(g[1]);
    int KB = 0;

    auto rowCoreF = [&](float2 c0, float2 c1, float2 c2) {
        const float u9 = u9n;
        const float p0 = c0.x;
        a[9] = (a[9] + a[8] + skipf[4] * a[7]) * c2.y;
        u9n = dpp_mov0<0x138>(a[9]);   // wave_shr:1 (lane0 -> 0)
        a[8] = (a[8] + a[7]) * p0;
        a[7] = (a[7] + a[6] + skipf[3] * a[5]) * c2.x;
        a[6] = (a[6] + a[5]) * p0;
        a[5] = (a[5] + a[4] + skipf[2] * a[3]) * c1.y;
        a[4] = (a[4] + a[3]) * p0;
        a[3] = (a[3] + a[2] + skipf[1] * a[1]) * c1.x;
        a[2] = (a[2] + a[1]) * p0;
        a[1] = (a[1] + a[0] + skipf[0] * u9) * c0.y;
        a[0] = (a[0] + u9) * p0;
    };
    auto rowCoreB = [&](float2 c0, float2 c1, float2 c2) {
        const float d0 = d0n, d1 = d1n;
        const float p0 = c0.x;
        g[0] = (g[0] + g[1]) * p0;
        g[1] = (g[1] + g[2] + sB[0] * g[3]) * c0.y;
        d0n = dpp_mov0<0x130>(g[0]);
        d1n = dpp_mov0<0x130>(g[1]);
        g[2] = (g[2] + g[3]) * p0;
        g[3] = (g[3] + g[4] + sB[1] * g[5]) * c1.x;
        g[4] = (g[4] + g[5]) * p0;
        g[5] = (g[5] + g[6] + sB[2] * g[7]) * c1.y;
        g[6] = (g[6] + g[7]) * p0;
        g[7] = (g[7] + g[8] + sB[3] * g[9]) * c2.x;
        g[8] = (g[8] + g[9]) * p0;
        g[9] = (g[9] + d0 + sB[4] * d1) * c2.y;
    };

    float2 SF[2][12], SB2[2][12];     // [set][row*3+plane], const-indexed
    auto readBlocks = [&](int set, int m) {
        const int base = ((4 * m) & (GRING - 1)) * ROWF + 2 * lane;
        #pragma unroll
        for (int r = 0; r < 4; ++r)
            #pragma unroll
            for (int pl = 0; pl < 3; ++pl) {
                SF[set][r * 3 + pl]  = *(const float2*)&ringF[base + r * ROWF + pl * 128];
                SB2[set][r * 3 + pl] = *(const float2*)&ringB[base + r * ROWF + pl * 128];
            }
    };
    // body: poll+prefetch block m+1 into setp, consume block m from setc
    // (fwd and bwd rows interleaved -- independent chains fill each other's
    // latency), publish cons.
    auto body = [&](int m, int setc, int setp) {
        if (4 * (m + 1) + 1 <= Umax) {
            poll_eq(&tags[(m + 1) & (NTAG - 1)], m + 1);
            readBlocks(setp, m + 1);
        }
        #pragma unroll
        for (int r = 0; r < 4; ++r) {
            const int u = 4 * m + 1 + r;
            if (u <= Uf)
                rowCoreF(SF[setc][r * 3], SF[setc][r * 3 + 1], SF[setc][r * 3 + 2]);
            if (u <= Ub)
                rowCoreB(SB2[setc][r * 3], SB2[setc][r * 3 + 1], SB2[setc][r * 3 + 2]);
        }
        if (lane == 0)
            __hip_atomic_store(&cons, 4 * m + 4, __ATOMIC_RELAXED, WG_SCOPE);
    };

    const int MB = (Umax + 3) >> 2;   // total blocks (>= 96)
    poll_eq(&tags[0], 0); readBlocks(0, 0);
    for (int m = 0; m < MB; m += 2) {
        body(m, 0, 1);
        if (m + 1 < MB) body(m + 1, 1, 0);
        {   // rescale both scans (chains interleave); cadence <= 8 rows
            const int ksF = wave_rescale(a, KF); u9n = ldexpf(u9n, ksF);
            const int ksB = wave_rescale(g, KB);
            d0n = ldexpf(d0n, ksB); d1n = ldexpf(d1n, ksB);
        }
    }

    {   // combine: gext[s] = g[s] + g[s+1] + skip[s+2]*g[s+2] (ascending)
        const float d0 = d0n, d1 = d1n;
        g[0] = g[0] + g[1];
        g[1] = g[1] + g[2] + sB[0] * g[3];
        g[2] = g[2] + g[3];
        g[3] = g[3] + g[4] + sB[1] * g[5];
        g[4] = g[4] + g[5];
        g[5] = g[5] + g[6] + sB[2] * g[7];
        g[6] = g[6] + g[7];
        g[7] = g[7] + g[8] + sB[3] * g[9];
        g[8] = g[8] + g[9];
        g[9] = g[9] + d0 + sB[4] * d1;
    }

    // ---- in-register join: sum_s alpha[s] * gext[s] in DOUBLE (R7 lesson) ----
    double sum = 0.0;
    #pragma unroll
    for (int k = 0; k < 10; ++k)
        sum += (double)a[k] * (double)g[k];
    #pragma unroll
    for (int d = 1; d < 64; d <<= 1) sum += __shfl_xor(sum, d, 64);
    if (lane == 0) {
        float lossv = 0.0f;                    // infeasible (sum<=0) -> 0
        if (sum > 0.0) {
            const long long ub = __double_as_longlong(sum);
            const int ex = (int)((ub >> 52) & 2047) - 1023;
            const double f = __longlong_as_double(
                (ub & 0x000FFFFFFFFFFFFFLL) | 0x3FF0000000000000LL);
            const float ll2 = __builtin_log2f((float)f)
                            + (float)(ex - KF - KB);
            lossv = -(ll2 * LN2);
            if (!(lossv <= 1e29f)) lossv = 0.0f;   // zero_infinity
        }
        loss[b] = lossv / (float)L;
    }
}

__global__ void ctc_reduce_kernel(const float* __restrict__ ws, float* __restrict__ out) {
    float v = ws[threadIdx.x];
    #pragma unroll
    for (int o = 32; o > 0; o >>= 1) v += __shfl_down(v, o);
    if (threadIdx.x == 0) out[0] = v / (float)B_;
}

extern "C" void kernel_launch(void* const* d_in, const int* in_sizes, int n_in,
                              void* d_out, int out_size, void* d_ws, size_t ws_size,
                              hipStream_t stream) {
    const float* lp      = (const float*)d_in[0];
    const int*   in_len  = (const int*)d_in[1];
    const int*   tgt     = (const int*)d_in[2];
    const int*   tgt_len = (const int*)d_in[3];
    float* lossArr = (float*)d_ws;              // 64 floats
    float* out     = (float*)d_out;

    ctc_scan<<<B_, 256, 0, stream>>>(lp, in_len, tgt, tgt_len, lossArr);
    ctc_reduce_kernel<<<1, 64, 0, stream>>>(lossArr, out);
}

// Round 13
// 143.702 us; speedup vs baseline: 1.6809x; 1.3928x over previous
//
#include <hip/hip_runtime.h>

// Problem constants (fixed by setup_inputs): B=64, T=1024, V=128, S=256
constexpr int B_ = 64;
constexpr int T_ = 1024;
constexpr int V_ = 128;
constexpr int S_ = 256;
constexpr int GRING = 64;            // ring rows (4 superblocks of 16)
constexpr int ROWF = 384;            // floats/row: 256 (f4 plane) + 128 (f2 plane)
constexpr int NTAG = 4;              // superblock tags
constexpr int NGW = 3;               // producer waves
constexpr float INV_LN2 = 1.4426950408889634f;
constexpr float LN2 = 0.6931471805599453f;

// Workspace layout (floats): [0..63] unused; [64 ..) dumps: fwd b*640,
// bwd at +64*640; K exponents as ints after (fwd [b], bwd [64+b]).
#define WS_DUMPF(W, b) ((W) + 64 + (size_t)(b) * 640)
#define WS_DUMPB(W, b) ((W) + 64 + 64 * 640 + (size_t)(b) * 640)
#define WS_KARR(W)     ((int*)((W) + 64 + 2 * 64 * 640))

#define WG_SCOPE __HIP_MEMORY_SCOPE_WORKGROUP

__device__ __forceinline__ void poll_eq(int* p, int want) {
    // RELAXED: LDS is per-CU; producer drained ds_writes (lgkmcnt(0)) before tag.
    while (__hip_atomic_load(p, __ATOMIC_RELAXED, WG_SCOPE) != want)
        __builtin_amdgcn_s_sleep(1);
}

// ---- DPP cross-lane helpers (pure VALU: no DS op, no lgkmcnt) ----
template <int CTRL>
__device__ __forceinline__ float dpp_mov0(float x) {
    // invalid source lanes receive old = 0 (wave_shr1: lane0 -> 0;
    // wave_shl1: lane63 -> 0) -- exactly the boundary fill the scan needs.
    return __int_as_float(__builtin_amdgcn_update_dpp(
        0, __float_as_int(x), CTRL, 0xF, 0xF, false));
}
template <int CTRL>
__device__ __forceinline__ float dpp_max(float x) {
    const float s = __int_as_float(__builtin_amdgcn_update_dpp(
        __float_as_int(x), __float_as_int(x), CTRL, 0xF, 0xF, false));
    return fmaxf(x, s);
}

// Wave-uniform rescale: pin wave max to 2^124. CADENCE MUST BE <= 8 ROWS:
// R21 LESSON (absmax 14): at 16-row cadence a tail stretch of low-prob
// labels (~17 bits/row decay) flushes the ENTIRE state vector to 0 ->
// that batch's loss becomes 0 (zero_infinity). R9 failed the same way.
// 8-row cadence needs 34 bits/row sustained to die -- never observed
// (six rounds absmax=0). Do not raise this cadence again.
__device__ __forceinline__ int wave_rescale(float a[10], int& K) {
    float mx = a[0];
    #pragma unroll
    for (int k = 1; k < 10; ++k) mx = fmaxf(mx, a[k]);
    mx = dpp_max<0x111>(mx);   // row_shr:1
    mx = dpp_max<0x112>(mx);   // row_shr:2
    mx = dpp_max<0x114>(mx);   // row_shr:4
    mx = dpp_max<0x118>(mx);   // row_shr:8
    mx = dpp_max<0x142>(mx);   // row_bcast:15
    mx = dpp_max<0x143>(mx);   // row_bcast:31 -> lane63 has wave-max
    const float mall = __int_as_float(
        __builtin_amdgcn_readlane(__float_as_int(mx), 63));
    int e;
    (void)frexpf(mall, &e);
    const int ks = (mall > 0.0f) ? (124 - e) : 0;
    #pragma unroll
    for (int k = 0; k < 10; ++k) a[k] = ldexpf(a[k], ks);
    K += ks;
    return ks;
}

// R22 = R21 (instruction-minimized consumer) with 8-row rescale restored.
// R20 proved the lone scan wave is ISSUE-CADENCE bound (~5cy/instr), so
// time/row = stream length x cadence. Consumer stream cuts kept: packed
// f4+f2 row layout (2 ds_reads/row, imm offsets off one base per 8 rows),
// 16-row superblock tags (polls/cons-stores amortized 4x), unguarded main
// loop + guarded tail. 128 WGs x 4 waves (1 consumer + 3 producers),
// R13 elastic tag protocol.
__global__ __launch_bounds__(256) void ctc_scan(
    const float* __restrict__ lp,      // [B,T,V] natural-log softmax
    const int* __restrict__ in_len,    // [B]
    const int* __restrict__ tgt,       // [B,S]
    const int* __restrict__ tgt_len,   // [B]
    float* __restrict__ W)             // workspace
{
    const int b    = blockIdx.x & 63;
    const int dir  = blockIdx.x >> 6;         // 0 = fwd, 1 = bwd
    const int tid  = threadIdx.x;
    const int wid  = tid >> 6;
    const int lane = tid & 63;

    __shared__ float ring[GRING * ROWF];      // 96 KB
    __shared__ int   tags[NTAG];
    __shared__ int   cons;                    // rows consumed

    const int L  = tgt_len[b];        // 64..256
    const int Tb = in_len[b];         // 768..1024
    const float* lpb = lp + (size_t)b * T_ * V_;
    const int* tg = tgt + b * S_;

    const int tm = (Tb - 2) >> 1;
    const int Uf = tm;                // fwd steps: u=1..Uf (row t=u)
    const int Ub = Tb - 2 - tm;       // bwd steps: u=1..Ub (row t=Tb-1-u)
    const int U  = dir ? Ub : Uf;     // >= 383

    if (tid == 0) cons = 0;
    if (tid < NTAG) tags[tid] = -1;
    __syncthreads();

    if (wid >= 1) {
        // ======================= producers =======================
        // wave q handles superblocks h == q (mod 3); 16 rows each. Per row:
        // coalesced float2 load -> 2 exp -> bpermute gather -> f4+f2 write.
        const int q = wid - 1;                    // 0..2

        int   perm[5], oddc[5];
        float vmask[5];
        #pragma unroll
        for (int c = 0; c < 5; ++c) {
            const int j = 5 * lane + c;
            if (j < L) { const int lb = tg[j]; perm[c] = lb >> 1; oddc[c] = lb & 1; vmask[c] = 1.0f; }
            else       { perm[c] = 0; oddc[c] = 0; vmask[c] = 0.0f; }
        }

        float2 R0[16], R1[16];
        auto issue = [&](float2 (&R)[16], int h) {
            #pragma unroll
            for (int i = 0; i < 16; ++i) {
                const int u = 16 * h + 1 + i;
                if (u <= U) {
                    const int t = dir ? (Tb - 1 - u) : u;
                    R[i] = *(const float2*)(lpb + (size_t)t * V_ + 2 * lane);
                }
            }
        };
        auto process = [&](float2 (&R)[16], int h) {
            // ring-slot reuse gate: SB h shares slots with SB h-4
            while (__hip_atomic_load(&cons, __ATOMIC_RELAXED, WG_SCOPE) < 16 * h - 48)
                __builtin_amdgcn_s_sleep(1);
            #pragma unroll
            for (int i = 0; i < 16; ++i) {
                const int u = 16 * h + 1 + i;
                if (u <= U) {
                    const float e0 = __builtin_exp2f(R[i].x * INV_LN2);
                    const float e1 = __builtin_exp2f(R[i].y * INV_LN2);
                    const float p0 = __int_as_float(
                        __builtin_amdgcn_readfirstlane(__float_as_int(e0)));
                    float gv[5];
                    #pragma unroll
                    for (int c = 0; c < 5; ++c) {
                        const float lo = __shfl(e0, perm[c], 64);
                        const float hi = __shfl(e1, perm[c], 64);
                        gv[c] = vmask[c] * (oddc[c] ? hi : lo);
                    }
                    float* rb = ring + ((u - 1) & (GRING - 1)) * ROWF;
                    *(float4*)&rb[4 * lane] = make_float4(p0, gv[0], gv[1], gv[2]);
                    *(float2*)&rb[256 + 2 * lane] = make_float2(gv[3], gv[4]);
                }
            }
            // drain LDS writes only (NOT vmcnt), then publish the tag.
            asm volatile("s_waitcnt lgkmcnt(0)" ::: "memory");
            if (lane == 0)
                __hip_atomic_store(&tags[h & (NTAG - 1)], h, __ATOMIC_RELAXED, WG_SCOPE);
        };

        int m = q;
        if (16 * m + 1 <= U) {
            issue(R0, m);
            if (16 * (m + NGW) + 1 <= U) issue(R1, m + NGW);
            while (true) {
                process(R0, m);
                if (16 * (m + 2 * NGW) + 1 <= U) issue(R0, m + 2 * NGW);
                m += NGW;
                if (16 * m + 1 > U) break;
                process(R1, m);
                if (16 * (m + 2 * NGW) + 1 <= U) issue(R1, m + 2 * NGW);
                m += NGW;
                if (16 * m + 1 > U) break;
            }
        }
        return;
    }

    // ======================= consumer (wave0) =======================
    float4 A4[8], B4[8];
    float2 A2[8], B2[8];
    // readHalf: 8 rows of half j (rows 8j+1..8j+8) -> 16 ds reads, one base,
    // all row offsets immediate (r*1536B <= 10.7KB < 64KB imm range).
    auto readHalfA = [&](int j) {
        const int base = ((8 * j) & (GRING - 1)) * ROWF;
        #pragma unroll
        for (int r = 0; r < 8; ++r) {
            A4[r] = *(const float4*)&ring[base + r * ROWF + 4 * lane];
            A2[r] = *(const float2*)&ring[base + r * ROWF + 256 + 2 * lane];
        }
    };
    auto readHalfB = [&](int j) {
        const int base = ((8 * j) & (GRING - 1)) * ROWF;
        #pragma unroll
        for (int r = 0; r < 8; ++r) {
            B4[r] = *(const float4*)&ring[base + r * ROWF + 4 * lane];
            B2[r] = *(const float2*)&ring[base + r * ROWF + 256 + 2 * lane];
        }
    };

    const int NHfull = U >> 3;        // full 8-row halves (>= 47)
    const int lastH  = (U - 1) >> 3;  // last half containing any row

    if (dir == 0) {
        // -------- forward alpha --------
        float skipf[5];
        #pragma unroll
        for (int c = 0; c < 5; ++c) {
            const int j = 5 * lane + c;
            skipf[c] = (j >= 1 && j < L && tg[j] != tg[j - 1]) ? 1.0f : 0.0f;
        }
        float a[10];
        #pragma unroll
        for (int k = 0; k < 10; ++k) a[k] = 0.0f;
        {
            const float p00 = __builtin_exp2f(lpb[0] * INV_LN2);
            const float p01 = __builtin_exp2f(lpb[tg[0]] * INV_LN2);
            if (lane == 0) { a[0] = p00; a[1] = p01; }
        }
        float u9n = 0.0f;
        int K = 0;

        auto rowCore = [&](float2 c0, float2 c1, float2 c2) {
            const float u9 = u9n;
            const float p0 = c0.x;
            a[9] = (a[9] + a[8] + skipf[4] * a[7]) * c2.y;
            u9n = dpp_mov0<0x138>(a[9]);   // wave_shr:1 (lane0 -> 0)
            a[8] = (a[8] + a[7]) * p0;
            a[7] = (a[7] + a[6] + skipf[3] * a[5]) * c2.x;
            a[6] = (a[6] + a[5]) * p0;
            a[5] = (a[5] + a[4] + skipf[2] * a[3]) * c1.y;
            a[4] = (a[4] + a[3]) * p0;
            a[3] = (a[3] + a[2] + skipf[1] * a[1]) * c1.x;
            a[2] = (a[2] + a[1]) * p0;
            a[1] = (a[1] + a[0] + skipf[0] * u9) * c0.y;
            a[0] = (a[0] + u9) * p0;
        };
        auto consume8A = [&]() {
            #pragma unroll
            for (int r = 0; r < 8; ++r)
                rowCore(make_float2(A4[r].x, A4[r].y),
                        make_float2(A4[r].z, A4[r].w), A2[r]);
        };
        auto consume8B = [&]() {
            #pragma unroll
            for (int r = 0; r < 8; ++r)
                rowCore(make_float2(B4[r].x, B4[r].y),
                        make_float2(B4[r].z, B4[r].w), B2[r]);
        };

        poll_eq(&tags[0], 0);
        readHalfA(0);
        int j = 0;
        while (j + 2 <= NHfull) {
            { const int H = j + 1;
              if (H <= lastH) {
                  if ((H & 1) == 0) poll_eq(&tags[(H >> 1) & (NTAG - 1)], H >> 1);
                  readHalfB(H);
              } }
            consume8A();
            { const int ks = wave_rescale(a, K); u9n = ldexpf(u9n, ks); }  // 8 rows
            { const int H = j + 2;
              if (H <= lastH) {
                  if ((H & 1) == 0) poll_eq(&tags[(H >> 1) & (NTAG - 1)], H >> 1);
                  readHalfA(H);
              } }
            consume8B();
            { const int ks = wave_rescale(a, K); u9n = ldexpf(u9n, ks); }  // 8 rows
            if (lane == 0)
                __hip_atomic_store(&cons, 8 * (j + 2), __ATOMIC_RELAXED, WG_SCOPE);
            j += 2;
        }
        if (j < NHfull) {             // leftover full half (always in set A)
            consume8A();
            { const int ks = wave_rescale(a, K); u9n = ldexpf(u9n, ks); }
            if (lane == 0)
                __hip_atomic_store(&cons, 8 * (j + 1), __ATOMIC_RELAXED, WG_SCOPE);
            j++;
        }
        if (8 * NHfull < U) {         // tail rows (<=7), guarded, direct reads
            const int sb = (8 * NHfull) >> 4;
            poll_eq(&tags[sb & (NTAG - 1)], sb);
            for (int u = 8 * NHfull + 1; u <= U; ++u) {
                const int base = ((u - 1) & (GRING - 1)) * ROWF;
                const float4 v4 = *(const float4*)&ring[base + 4 * lane];
                const float2 v2 = *(const float2*)&ring[base + 256 + 2 * lane];
                rowCore(make_float2(v4.x, v4.y), make_float2(v4.z, v4.w), v2);
            }
        }

        float* dump = WS_DUMPF(W, b);
        #pragma unroll
        for (int k = 0; k < 10; ++k) dump[10 * lane + k] = a[k];
        if (lane == 0) WS_KARR(W)[b] = K;
    } else {
        // -------- backward beta --------
        float sB[5];
        #pragma unroll
        for (int c = 0; c < 5; ++c) {
            const int j = 5 * lane + c + 1;
            sB[c] = (j < L && tg[j] != tg[j - 1]) ? 1.0f : 0.0f;
        }
        float g[10];
        #pragma unroll
        for (int k = 0; k < 10; ++k) g[k] = 0.0f;
        {   // g_{Tb-1}: nonzero at s=2L (blank) and s=2L-1 (last label)
            const float pb = __builtin_exp2f(lpb[(size_t)(Tb - 1) * V_] * INV_LN2);
            const float pl = __builtin_exp2f(lpb[(size_t)(Tb - 1) * V_ + tg[L - 1]] * INV_LN2);
            #pragma unroll
            for (int k = 0; k < 10; ++k) {
                const int s = 10 * lane + k;
                if (s == 2 * L)     g[k] = pb;
                if (s == 2 * L - 1) g[k] = pl;
            }
        }
        float d0n = dpp_mov0<0x130>(g[0]);   // wave_shl:1 (lane63 -> 0)
        float d1n = dpp_mov0<0x130>(g[1]);
        int K = 0;

        auto rowCore = [&](float2 c0, float2 c1, float2 c2) {
            const float d0 = d0n, d1 = d1n;
            const float p0 = c0.x;
            g[0] = (g[0] + g[1]) * p0;
            g[1] = (g[1] + g[2] + sB[0] * g[3]) * c0.y;
            d0n = dpp_mov0<0x130>(g[0]);
            d1n = dpp_mov0<0x130>(g[1]);
            g[2] = (g[2] + g[3]) * p0;
            g[3] = (g[3] + g[4] + sB[1] * g[5]) * c1.x;
            g[4] = (g[4] + g[5]) * p0;
            g[5] = (g[5] + g[6] + sB[2] * g[7]) * c1.y;
            g[6] = (g[6] + g[7]) * p0;
            g[7] = (g[7] + g[8] + sB[3] * g[9]) * c2.x;
            g[8] = (g[8] + g[9]) * p0;
            g[9] = (g[9] + d0 + sB[4] * d1) * c2.y;
        };
        auto consume8A = [&]() {
            #pragma unroll
            for (int r = 0; r < 8; ++r)
                rowCore(make_float2(A4[r].x, A4[r].y),
                        make_float2(A4[r].z, A4[r].w), A2[r]);
        };
        auto consume8B = [&]() {
            #pragma unroll
            for (int r = 0; r < 8; ++r)
                rowCore(make_float2(B4[r].x, B4[r].y),
                        make_float2(B4[r].z, B4[r].w), B2[r]);
        };

        poll_eq(&tags[0], 0);
        readHalfA(0);
        int j = 0;
        while (j + 2 <= NHfull) {
            { const int H = j + 1;
              if (H <= lastH) {
                  if ((H & 1) == 0) poll_eq(&tags[(H >> 1) & (NTAG - 1)], H >> 1);
                  readHalfB(H);
              } }
            consume8A();
            { const int ks = wave_rescale(g, K);
              d0n = ldexpf(d0n, ks); d1n = ldexpf(d1n, ks); }              // 8 rows
            { const int H = j + 2;
              if (H <= lastH) {
                  if ((H & 1) == 0) poll_eq(&tags[(H >> 1) & (NTAG - 1)], H >> 1);
                  readHalfA(H);
              } }
            consume8B();
            { const int ks = wave_rescale(g, K);
              d0n = ldexpf(d0n, ks); d1n = ldexpf(d1n, ks); }              // 8 rows
            if (lane == 0)
                __hip_atomic_store(&cons, 8 * (j + 2), __ATOMIC_RELAXED, WG_SCOPE);
            j += 2;
        }
        if (j < NHfull) {
            consume8A();
            { const int ks = wave_rescale(g, K);
              d0n = ldexpf(d0n, ks); d1n = ldexpf(d1n, ks); }
            if (lane == 0)
                __hip_atomic_store(&cons, 8 * (j + 1), __ATOMIC_RELAXED, WG_SCOPE);
            j++;
        }
        if (8 * NHfull < U) {
            const int sb = (8 * NHfull) >> 4;
            poll_eq(&tags[sb & (NTAG - 1)], sb);
            for (int u = 8 * NHfull + 1; u <= U; ++u) {
                const int base = ((u - 1) & (GRING - 1)) * ROWF;
                const float4 v4 = *(const float4*)&ring[base + 4 * lane];
                const float2 v2 = *(const float2*)&ring[base + 256 + 2 * lane];
                rowCore(make_float2(v4.x, v4.y), make_float2(v4.z, v4.w), v2);
            }
        }

        {   // combine: gext[s] = g[s] + g[s+1] + skip[s+2]*g[s+2] (ascending)
            const float d0 = d0n, d1 = d1n;
            g[0] = g[0] + g[1];
            g[1] = g[1] + g[2] + sB[0] * g[3];
            g[2] = g[2] + g[3];
            g[3] = g[3] + g[4] + sB[1] * g[5];
            g[4] = g[4] + g[5];
            g[5] = g[5] + g[6] + sB[2] * g[7];
            g[6] = g[6] + g[7];
            g[7] = g[7] + g[8] + sB[3] * g[9];
            g[8] = g[8] + g[9];
            g[9] = g[9] + d0 + sB[4] * d1;
        }
        float* dump = WS_DUMPB(W, b);
        #pragma unroll
        for (int k = 0; k < 10; ++k) dump[10 * lane + k] = g[k];
        if (lane == 0) WS_KARR(W)[64 + b] = K;
    }
}

// Fused join + reduce: ONE block, 256 threads. Thread (b = tid&63, q = tid>>6)
// accumulates a quarter of the 640-term dot in double; 4-way LDS combine;
// lanes 0..63 finish per-b loss; wave-reduce mean. Saves a launch (~10-15us).
__global__ void ctc_join_reduce(const float* __restrict__ W,
                                const int* __restrict__ tgt_len,
                                float* __restrict__ out) {
    const int tid = threadIdx.x;
    const int b   = tid & 63;
    const int q   = tid >> 6;
    const float* dA = WS_DUMPF(W, b);
    const float* dB = WS_DUMPB(W, b);
    double part = 0.0;
    #pragma unroll 4
    for (int k = 160 * q; k < 160 * q + 160; ++k)
        part += (double)dA[k] * (double)dB[k];
    __shared__ double sh[256];
    sh[tid] = part;
    __syncthreads();
    if (tid < 64) {
        const double sum = sh[tid] + sh[tid + 64] + sh[tid + 128] + sh[tid + 192];
        const int L  = tgt_len[b];
        const int KF = WS_KARR(W)[b];
        const int KB = WS_KARR(W)[64 + b];
        float lossv = 0.0f;                    // infeasible (sum<=0) -> 0
        if (sum > 0.0) {
            const long long ub = __double_as_longlong(sum);
            const int ex = (int)((ub >> 52) & 2047) - 1023;
            const double f = __longlong_as_double(
                (ub & 0x000FFFFFFFFFFFFFLL) | 0x3FF0000000000000LL);
            const float ll2 = __builtin_log2f((float)f)
                            + (float)(ex - KF - KB);
            lossv = -(ll2 * LN2);
            if (!(lossv <= 1e29f)) lossv = 0.0f;   // zero_infinity
        }
        float v = lossv / (float)L;
        #pragma unroll
        for (int d = 1; d < 64; d <<= 1) v += __shfl_xor(v, d, 64);
        if (tid == 0) out[0] = v / (float)B_;
    }
}

extern "C" void kernel_launch(void* const* d_in, const int* in_sizes, int n_in,
                              void* d_out, int out_size, void* d_ws, size_t ws_size,
                              hipStream_t stream) {
    const float* lp      = (const float*)d_in[0];
    const int*   in_len  = (const int*)d_in[1];
    const int*   tgt     = (const int*)d_in[2];
    const int*   tgt_len = (const int*)d_in[3];
    float* W   = (float*)d_ws;                  // needs ~330 KB
    float* out = (float*)d_out;

    ctc_scan<<<2 * B_, 256, 0, stream>>>(lp, in_len, tgt, tgt_len, W);
    ctc_join_reduce<<<1, 256, 0, stream>>>(W, tgt_len, out);
}